// Round 15
// baseline (187.636 us; speedup 1.0000x reference)
//
#include <hip/hip_runtime.h>
#include <hip/hip_fp16.h>
#include <math.h>
#include <stdint.h>

#define NH    8
#define HD    64
#define NTOK  4096   // D*H*W = 16^3
#define CDIM  512
#define NSAMP 27

typedef __attribute__((ext_vector_type(8))) _Float16 half8;
typedef __attribute__((ext_vector_type(4))) float floatx4;
typedef unsigned short ushort_t;

__device__ __forceinline__ ushort_t f16b(float f) {
  return __half_as_ushort(__float2half(f));
}
__device__ __forceinline__ __half2 u2h2(uint32_t u) { return __builtin_bit_cast(__half2, u); }
__device__ __forceinline__ uint32_t h22u(__half2 h) { return __builtin_bit_cast(uint32_t, h); }

// convert 8 consecutive fp32 -> uint4 of 8 packed f16
__device__ __forceinline__ uint4 cvt8(const float* __restrict__ p) {
  float4 a = *(const float4*)p;
  float4 b = *(const float4*)(p + 4);
  uint4 o;
  o.x = (uint32_t)f16b(a.x) | ((uint32_t)f16b(a.y) << 16);
  o.y = (uint32_t)f16b(a.z) | ((uint32_t)f16b(a.w) << 16);
  o.z = (uint32_t)f16b(b.x) | ((uint32_t)f16b(b.y) << 16);
  o.w = (uint32_t)f16b(b.z) | ((uint32_t)f16b(b.w) << 16);
  return o;
}

// Full 64-lane sum via DPP; result uniform via readlane(63)  [R8 form]
__device__ __forceinline__ float wave_sum_bcast(float x) {
#define DPP_STEP(ctrl, rmask)                                                   \
  { int t = __builtin_amdgcn_update_dpp(0, __float_as_int(x), ctrl, rmask, 0xf, \
                                        true);                                  \
    x += __int_as_float(t); }
  DPP_STEP(0x111, 0xf)  // row_shr:1
  DPP_STEP(0x112, 0xf)  // row_shr:2
  DPP_STEP(0x114, 0xf)  // row_shr:4
  DPP_STEP(0x118, 0xf)  // row_shr:8
  DPP_STEP(0x142, 0xa)  // row_bcast:15
  DPP_STEP(0x143, 0xc)  // row_bcast:31 -> lane63 = total
#undef DPP_STEP
  return __int_as_float(__builtin_amdgcn_readlane(__float_as_int(x), 63));
}

// ============ Kernel 1: fused pre-attention (qkv + offsets + pos), inline f16 cvt ======
// blocks 0..767:    qkv 64x128 tiles (bm = id&63, bn = id>>6; bn<4: q, else kv head)
// blocks 768..1023: off GEMM per head (bm = &31, h = >>5), K=64
// blocks 1024..1279: pos GEMM per head; recomputes its q-tile (K=512) then P (K=64)
__global__ __launch_bounds__(256) void k_pre(const float* __restrict__ x,
                                             const float* __restrict__ w_qkv,
                                             const float* __restrict__ w_off,
                                             const float* __restrict__ rel_d,
                                             const float* __restrict__ rel_h,
                                             const float* __restrict__ rel_w,
                                             ushort_t* __restrict__ qh16,
                                             uint32_t* __restrict__ kvb,
                                             float* __restrict__ ob,
                                             float* __restrict__ Pb) {
  __shared__ __align__(16) char smem[36864];
  const int tid = threadIdx.x;
  const int wave = tid >> 6, lane = tid & 63;
  const int wr = wave >> 1, wc = wave & 1;
  const int m15 = lane & 15, quad = lane >> 4;
  const int bid = blockIdx.x;
  const int r0 = tid >> 2, c0 = (tid & 3) * 8;

  if (bid < 768) {
    // ---------------- qkv path (R14 structure, fp32 staging) ----------------
    const int bm = bid & 63, bn = bid >> 6;
    const bool is_q = (bn < 4);
    const int h = bn - 4;
    ushort_t* As = (ushort_t*)smem;                    // 64 x 32
    ushort_t* Bs = (ushort_t*)(smem + 4096);           // 128 x 32
    ushort_t* Cs = (ushort_t*)(smem + 4096 + 8192);    // 64 x 136
    floatx4 acc[2][4];
#pragma unroll
    for (int i = 0; i < 2; i++)
#pragma unroll
      for (int j = 0; j < 4; j++) acc[i][j] = {0.f, 0.f, 0.f, 0.f};

    const int brA = is_q ? (bn * 128 + r0) : (512 + h * 64 + r0);
    const int brB = is_q ? (bn * 128 + 64 + r0) : (1024 + h * 64 + r0);
    for (int k0 = 0; k0 < 512; k0 += 32) {
      *(uint4*)&As[r0 * 32 + c0] = cvt8(&x[(size_t)(bm * 64 + r0) * 512 + k0 + c0]);
      *(uint4*)&Bs[r0 * 32 + c0]        = cvt8(&w_qkv[(size_t)brA * 512 + k0 + c0]);
      *(uint4*)&Bs[(r0 + 64) * 32 + c0] = cvt8(&w_qkv[(size_t)brB * 512 + k0 + c0]);
      __syncthreads();
      half8 af[2], bf[4];
#pragma unroll
      for (int i = 0; i < 2; i++)
        af[i] = *(const half8*)&As[(wr * 32 + i * 16 + m15) * 32 + quad * 8];
#pragma unroll
      for (int j = 0; j < 4; j++)
        bf[j] = *(const half8*)&Bs[(wc * 64 + j * 16 + m15) * 32 + quad * 8];
#pragma unroll
      for (int i = 0; i < 2; i++)
#pragma unroll
        for (int j = 0; j < 4; j++)
          acc[i][j] = __builtin_amdgcn_mfma_f32_16x16x32_f16(af[i], bf[j], acc[i][j], 0, 0, 0);
      __syncthreads();
    }
#pragma unroll
    for (int i = 0; i < 2; i++)
#pragma unroll
      for (int j = 0; j < 4; j++) {
        int col = wc * 64 + j * 16 + m15;
#pragma unroll
        for (int r = 0; r < 4; r++) {
          int row = wr * 32 + i * 16 + quad * 4 + r;
          Cs[row * 136 + col] = f16b(acc[i][j][r]);
        }
      }
    __syncthreads();
    if (is_q) {
#pragma unroll
      for (int it = 0; it < 4; it++) {
        int id = it * 256 + tid;
        int hh = id >> 9, row = (id >> 3) & 63, chunk = id & 7;
        uint4 d = *(const uint4*)&Cs[row * 136 + hh * 64 + chunk * 8];
        int hq = bn * 2 + hh;
        *(uint4*)&qh16[((size_t)hq * NTOK + bm * 64 + row) * 64 + chunk * 8] = d;
      }
    } else {
#pragma unroll
      for (int it = 0; it < 4; it++) {
        int id = it * 256 + tid;
        int row = id >> 4, chunk = id & 15;
        uint2 kk = *(const uint2*)&Cs[row * 136 + chunk * 4];
        uint2 vv = *(const uint2*)&Cs[row * 136 + 64 + chunk * 4];
        uint4 o;
        o.x = (kk.x & 0xffffu) | (vv.x << 16);
        o.y = (kk.x >> 16) | (vv.x & 0xffff0000u);
        o.z = (kk.y & 0xffffu) | (vv.y << 16);
        o.w = (kk.y >> 16) | (vv.y & 0xffff0000u);
        *(uint4*)&kvb[((size_t)h * NTOK + bm * 64 + row) * 64 + chunk * 4] = o;
      }
    }
  } else if (bid < 1024) {
    // ---------------- off path: ob_h = x[:, h*64:+64] @ w_off^T, K=64 ----------------
    const int b2 = bid - 768;
    const int bm = b2 & 31, h = b2 >> 5;
    ushort_t* As = (ushort_t*)smem;                 // 128 x 32
    ushort_t* Bs = (ushort_t*)(smem + 8192);        // 128 x 32
    floatx4 acc[4][4];
#pragma unroll
    for (int i = 0; i < 4; i++)
#pragma unroll
      for (int j = 0; j < 4; j++) acc[i][j] = {0.f, 0.f, 0.f, 0.f};
    const int r1 = r0 + 64;
    const uint4 z4 = {0u, 0u, 0u, 0u};
    for (int k0 = 0; k0 < 64; k0 += 32) {
      *(uint4*)&As[r0 * 32 + c0] = cvt8(&x[(size_t)(bm * 128 + r0) * 512 + h * 64 + k0 + c0]);
      *(uint4*)&As[r1 * 32 + c0] = cvt8(&x[(size_t)(bm * 128 + r1) * 512 + h * 64 + k0 + c0]);
      *(uint4*)&Bs[r0 * 32 + c0] = (r0 < 81) ? cvt8(&w_off[r0 * 64 + k0 + c0]) : z4;
      *(uint4*)&Bs[r1 * 32 + c0] = (r1 < 81) ? cvt8(&w_off[r1 * 64 + k0 + c0]) : z4;
      __syncthreads();
      half8 af[4], bf[4];
#pragma unroll
      for (int i = 0; i < 4; i++)
        af[i] = *(const half8*)&As[(wr * 64 + i * 16 + m15) * 32 + quad * 8];
#pragma unroll
      for (int j = 0; j < 4; j++)
        bf[j] = *(const half8*)&Bs[(wc * 64 + j * 16 + m15) * 32 + quad * 8];
#pragma unroll
      for (int i = 0; i < 4; i++)
#pragma unroll
        for (int j = 0; j < 4; j++)
          acc[i][j] = __builtin_amdgcn_mfma_f32_16x16x32_f16(af[i], bf[j], acc[i][j], 0, 0, 0);
      __syncthreads();
    }
#pragma unroll
    for (int i = 0; i < 4; i++)
#pragma unroll
      for (int j = 0; j < 4; j++) {
        int col = wc * 64 + j * 16 + m15;
        if (col < 81) {
#pragma unroll
          for (int r = 0; r < 4; r++) {
            int row = bm * 128 + wr * 64 + i * 16 + quad * 4 + r;
            ob[((size_t)h * NTOK + row) * 81 + col] = acc[i][j][r];
          }
        }
      }
  } else {
    // ---------------- pos path: recompute q-tile, then P_h = q @ rel^T ----------------
    const int b2 = bid - 1024;
    const int bm = b2 & 31, h = b2 >> 5;
    ushort_t* Qs = (ushort_t*)smem;                   // 128 x 72 (18432 B)
    ushort_t* As = (ushort_t*)(smem + 18432);         // 128 x 32 (phase 1)
    ushort_t* Bq = (ushort_t*)(smem + 18432 + 8192);  // 64 x 32  (phase 1)
    ushort_t* Br = (ushort_t*)(smem + 18432);         // 128 x 72 (phase 2, reuses As/Bq)
    const int r1 = r0 + 64;

    // phase 1: q_tile(128x64) = x(128x512) @ Wq_h(64x512)^T ; waves 2x2, 64x32 each
    floatx4 qacc[4][2];
#pragma unroll
    for (int i = 0; i < 4; i++)
#pragma unroll
      for (int j = 0; j < 2; j++) qacc[i][j] = {0.f, 0.f, 0.f, 0.f};
    for (int k0 = 0; k0 < 512; k0 += 32) {
      *(uint4*)&As[r0 * 32 + c0] = cvt8(&x[(size_t)(bm * 128 + r0) * 512 + k0 + c0]);
      *(uint4*)&As[r1 * 32 + c0] = cvt8(&x[(size_t)(bm * 128 + r1) * 512 + k0 + c0]);
      *(uint4*)&Bq[r0 * 32 + c0] = cvt8(&w_qkv[(size_t)(h * 64 + r0) * 512 + k0 + c0]);
      __syncthreads();
      half8 af[4], bf[2];
#pragma unroll
      for (int i = 0; i < 4; i++)
        af[i] = *(const half8*)&As[(wr * 64 + i * 16 + m15) * 32 + quad * 8];
#pragma unroll
      for (int j = 0; j < 2; j++)
        bf[j] = *(const half8*)&Bq[(wc * 32 + j * 16 + m15) * 32 + quad * 8];
#pragma unroll
      for (int i = 0; i < 4; i++)
#pragma unroll
        for (int j = 0; j < 2; j++)
          qacc[i][j] = __builtin_amdgcn_mfma_f32_16x16x32_f16(af[i], bf[j], qacc[i][j], 0, 0, 0);
      __syncthreads();
    }
    // q-tile -> Qs (f16, stride 72)
#pragma unroll
    for (int i = 0; i < 4; i++)
#pragma unroll
      for (int j = 0; j < 2; j++) {
        int col = wc * 32 + j * 16 + m15;
#pragma unroll
        for (int r = 0; r < 4; r++) {
          int row = wr * 64 + i * 16 + quad * 4 + r;
          Qs[row * 72 + col] = f16b(qacc[i][j][r]);
        }
      }
    // stage rel (126 rows padded to 128, stride 72)
    const uint4 z4 = {0u, 0u, 0u, 0u};
#pragma unroll
    for (int kk = 0; kk < 64; kk += 32) {
#pragma unroll
      for (int half = 0; half < 2; half++) {
        int rr = r0 + half * 64;
        uint4 v = z4;
        if (rr < 42)       v = cvt8(&rel_w[rr * 64 + kk + c0]);
        else if (rr < 84)  v = cvt8(&rel_h[(rr - 42) * 64 + kk + c0]);
        else if (rr < 126) v = cvt8(&rel_d[(rr - 84) * 64 + kk + c0]);
        *(uint4*)&Br[rr * 72 + kk + c0] = v;
      }
    }
    __syncthreads();
    // phase 2: P(128x126) = q(128x64) @ rel(126x64)^T ; waves 2x2, 64x64 each
    floatx4 pacc[4][4];
#pragma unroll
    for (int i = 0; i < 4; i++)
#pragma unroll
      for (int j = 0; j < 4; j++) pacc[i][j] = {0.f, 0.f, 0.f, 0.f};
#pragma unroll
    for (int kk = 0; kk < 64; kk += 32) {
      half8 af[4], bf[4];
#pragma unroll
      for (int i = 0; i < 4; i++)
        af[i] = *(const half8*)&Qs[(wr * 64 + i * 16 + m15) * 72 + kk + quad * 8];
#pragma unroll
      for (int j = 0; j < 4; j++)
        bf[j] = *(const half8*)&Br[(wc * 64 + j * 16 + m15) * 72 + kk + quad * 8];
#pragma unroll
      for (int i = 0; i < 4; i++)
#pragma unroll
        for (int j = 0; j < 4; j++)
          pacc[i][j] = __builtin_amdgcn_mfma_f32_16x16x32_f16(af[i], bf[j], pacc[i][j], 0, 0, 0);
    }
#pragma unroll
    for (int i = 0; i < 4; i++)
#pragma unroll
      for (int j = 0; j < 4; j++) {
        int col = wc * 64 + j * 16 + m15;
        if (col < 126) {
#pragma unroll
          for (int r = 0; r < 4; r++) {
            int row = bm * 128 + wr * 64 + i * 16 + quad * 4 + r;
            Pb[((size_t)h * NTOK + row) * 126 + col] = pacc[i][j][r];
          }
        }
      }
  }
}

// ============ Kernel 2: fused deformable attention — exact R8/R12 structure ============
__global__ __launch_bounds__(256) void k_attn(const ushort_t* __restrict__ qh16,
                                              const uint32_t* __restrict__ kvb,
                                              const float* __restrict__ obuf,
                                              const float* __restrict__ Pbuf,
                                              ushort_t* __restrict__ attb16) {
  __shared__ int      s_off[4][NSAMP][8];   // BYTE offsets (voxel*256)
  __shared__ uint32_t s_cwh[4][NSAMP][8];   // half2(w,w) splats
  __shared__ uint32_t vpair[4][14][64];     // half2(v[2p], v[2p+1]) per channel
  __shared__ uint32_t s_wp[4][14];          // half2(w[2p], w[2p+1])
  const int bid = blockIdx.x;
  const int h = bid & 7;
  const int wave = threadIdx.x >> 6;
  const int lane = threadIdx.x & 63;
  const int n = (bid >> 3) * 4 + wave;
  const int z = n >> 8, y = (n >> 4) & 15, xq = n & 15;
  const float qd = __half2float(__ushort_as_half(qh16[((size_t)h * NTOK + n) * 64 + lane]));
  const char* kvc = (const char*)(kvb + (size_t)h * NTOK * 64);
  const uint32_t lane4 = (uint32_t)lane * 4u;

  if (lane < NSAMP) {
    const int s = lane;
    const float* op = &obuf[((size_t)h * NTOK + n) * 81 + s * 3];
    float oz = op[0], oy = op[1], ox = op[2];
    float pz = (float)(z + (s / 9) - 1) + oz;
    float py = (float)(y + ((s / 3) % 3) - 1) + oy;
    float px = (float)(xq + (s % 3) - 1) + ox;
    float fz = floorf(pz), fy = floorf(py), fx = floorf(px);
    float wz = pz - fz, wy = py - fy, wx = px - fx;
    int z0 = (int)fz, y0 = (int)fy, x0 = (int)fx;
    int      oarr[8];
    uint32_t warr[8];
#pragma unroll
    for (int c = 0; c < 8; c++) {
      int dz = (c >> 2) & 1, dy = (c >> 1) & 1, dx = c & 1;
      int zi = z0 + dz, yi = y0 + dy, xi = x0 + dx;
      bool valid = (zi >= 0) && (zi < 16) && (yi >= 0) && (yi < 16) && (xi >= 0) && (xi < 16);
      float w = (dz ? wz : 1.f - wz) * (dy ? wy : 1.f - wy) * (dx ? wx : 1.f - wx);
      int zc = min(max(zi, 0), 15), yc = min(max(yi, 0), 15), xc = min(max(xi, 0), 15);
      oarr[c] = ((zc * 16 + yc) * 16 + xc) * 256;       // byte offset of voxel row
      uint32_t hw = (uint32_t)f16b(valid ? w : 0.f);
      warr[c] = hw | (hw << 16);                        // half2(w, w)
    }
    *(int4*)&s_off[wave][s][0]  = make_int4(oarr[0], oarr[1], oarr[2], oarr[3]);
    *(int4*)&s_off[wave][s][4]  = make_int4(oarr[4], oarr[5], oarr[6], oarr[7]);
    *(uint4*)&s_cwh[wave][s][0] = make_uint4(warr[0], warr[1], warr[2], warr[3]);
    *(uint4*)&s_cwh[wave][s][4] = make_uint4(warr[4], warr[5], warr[6], warr[7]);
  }
  // no __syncthreads: producers/consumers are the same wave (in-order ds)

  float mydot = 0.f;
  uint32_t prev_acc = 0;
#pragma unroll 2
  for (int s = 0; s < NSAMP; s++) {
    int4  o0 = *(const int4*)&s_off[wave][s][0];
    int4  o1 = *(const int4*)&s_off[wave][s][4];
    uint4 c0 = *(const uint4*)&s_cwh[wave][s][0];
    uint4 c1 = *(const uint4*)&s_cwh[wave][s][4];
    __half2 acc2 = u2h2(0u);
    uint32_t p;
#define CORNER(OV, WV)                                                       \
    p = *(const uint32_t*)(kvc + (uint32_t)((uint32_t)OV + lane4));          \
    acc2 = __hfma2(u2h2(WV), u2h2(p), acc2);
    CORNER(o0.x, c0.x) CORNER(o0.y, c0.y) CORNER(o0.z, c0.z) CORNER(o0.w, c0.w)
    CORNER(o1.x, c1.x) CORNER(o1.y, c1.y) CORNER(o1.z, c1.z) CORNER(o1.w, c1.w)
#undef CORNER
    float ak = __half2float(acc2.x);
    float tot = wave_sum_bcast(qd * ak);   // uniform (SGPR)
    mydot = (lane == s) ? tot : mydot;
    uint32_t au = h22u(acc2);
    if (s & 1)
      vpair[wave][s >> 1][lane] = (prev_acc >> 16) | (au & 0xffff0000u);
    else
      prev_acc = au;
  }
  vpair[wave][13][lane] = prev_acc >> 16;   // v[26] in low half, 0 in high

  float logit = -INFINITY;
  if (lane < NSAMP) {
    int j = 15 + lane - xq;
    int n2 = (z * 16 + xq) * 16 + y;
    int n3 = (xq * 16 + z) * 16 + y;
    float pos = Pbuf[((size_t)h * NTOK + n) * 126 + j]
              + Pbuf[((size_t)h * NTOK + n2) * 126 + 42 + j]
              + Pbuf[((size_t)h * NTOK + n3) * 126 + 84 + j];
    logit = mydot * 0.125f + pos;
  }

  float mx = logit;
#pragma unroll
  for (int off = 32; off >= 1; off >>= 1) mx = fmaxf(mx, __shfl_xor(mx, off, 64));
  float e = __expf(logit - mx);            // lanes >= 27: exp(-inf) = 0
  float sum = e;
#pragma unroll
  for (int off = 32; off >= 1; off >>= 1) sum += __shfl_xor(sum, off, 64);
  const float wgt = e / sum;
  uint32_t hw = (uint32_t)f16b(wgt);                       // lanes>=27 -> 0
  uint32_t nw = (uint32_t)__shfl_down((int)hw, 1, 64);     // next lane's weight
  if ((lane & 1) == 0 && lane < 28)
    s_wp[wave][lane >> 1] = hw | (nw << 16);

  __half2 out2 = u2h2(0u);
#pragma unroll
  for (int p2 = 0; p2 < 14; p2++) {
    __half2 v2 = u2h2(vpair[wave][p2][lane]);
    __half2 w2 = u2h2(s_wp[wave][p2]);
    out2 = __hfma2(w2, v2, out2);
  }
  float out = __half2float(out2.x) + __half2float(out2.y);
  attb16[(size_t)n * 512 + h * 64 + lane] = f16b(out);
}

// ============ Kernel 3: proj GEMM, 64x64 tiles, inline w_proj conversion ============
__global__ __launch_bounds__(256) void k_proj(const ushort_t* __restrict__ Ah,
                                              const float* __restrict__ Wp,
                                              const float* __restrict__ bias,
                                              float* __restrict__ out) {
  __shared__ __align__(16) ushort_t As[64 * 32];
  __shared__ __align__(16) ushort_t Bs[64 * 32];
  const int tid = threadIdx.x;
  const int wave = tid >> 6, lane = tid & 63;
  const int wr = wave >> 1, wc = wave & 1;
  const int m15 = lane & 15, quad = lane >> 4;
  const int bm = blockIdx.x, bn = blockIdx.y;
  floatx4 acc[2][2];
#pragma unroll
  for (int i = 0; i < 2; i++)
#pragma unroll
    for (int j = 0; j < 2; j++) acc[i][j] = {0.f, 0.f, 0.f, 0.f};

  const int r0 = tid >> 2, c0 = (tid & 3) * 8;
  for (int k0 = 0; k0 < 512; k0 += 32) {
    *(uint4*)&As[r0 * 32 + c0] = *(const uint4*)&Ah[(size_t)(bm * 64 + r0) * 512 + k0 + c0];
    *(uint4*)&Bs[r0 * 32 + c0] = cvt8(&Wp[(size_t)(bn * 64 + r0) * 512 + k0 + c0]);
    __syncthreads();
    half8 af[2], bf[2];
#pragma unroll
    for (int i = 0; i < 2; i++)
      af[i] = *(const half8*)&As[(wr * 32 + i * 16 + m15) * 32 + quad * 8];
#pragma unroll
    for (int j = 0; j < 2; j++)
      bf[j] = *(const half8*)&Bs[(wc * 32 + j * 16 + m15) * 32 + quad * 8];
#pragma unroll
    for (int i = 0; i < 2; i++)
#pragma unroll
      for (int j = 0; j < 2; j++)
        acc[i][j] = __builtin_amdgcn_mfma_f32_16x16x32_f16(af[i], bf[j], acc[i][j], 0, 0, 0);
    __syncthreads();
  }

#pragma unroll
  for (int i = 0; i < 2; i++)
#pragma unroll
    for (int j = 0; j < 2; j++) {
      int col = bn * 64 + wc * 32 + j * 16 + m15;
      float b = bias[col];
#pragma unroll
      for (int r = 0; r < 4; r++) {
        int row = bm * 64 + wr * 32 + i * 16 + quad * 4 + r;
        out[(size_t)row * 512 + col] = acc[i][j][r] + b;
      }
    }
}

extern "C" void kernel_launch(void* const* d_in, const int* in_sizes, int n_in,
                              void* d_out, int out_size, void* d_ws, size_t ws_size,
                              hipStream_t stream) {
  const float* x      = (const float*)d_in[0];
  const float* w_qkv  = (const float*)d_in[1];
  const float* w_proj = (const float*)d_in[2];
  const float* b_proj = (const float*)d_in[3];
  const float* w_off  = (const float*)d_in[4];
  const float* rel_d  = (const float*)d_in[5];
  const float* rel_h  = (const float*)d_in[6];
  const float* rel_w  = (const float*)d_in[7];

  char* ws = (char*)d_ws;
  uint32_t* kvb    = (uint32_t*)ws; ws += (size_t)NH * NTOK * 64 * 4;
  float*    ob     = (float*)ws;    ws += (size_t)NH * NTOK * 81 * 4;
  float*    Pb     = (float*)ws;    ws += (size_t)NH * NTOK * 126 * 4;
  ushort_t* attb16 = (ushort_t*)ws; ws += (size_t)NTOK * CDIM * 2;
  ushort_t* qh16   = (ushort_t*)ws; ws += (size_t)NH * NTOK * 64 * 2;
  float*    out    = (float*)d_out;

  k_pre <<<dim3(1280),  dim3(256), 0, stream>>>(x, w_qkv, w_off, rel_d, rel_h, rel_w,
                                                qh16, kvb, ob, Pb);
  k_attn<<<dim3(8192),  dim3(256), 0, stream>>>(qh16, kvb, ob, Pb, attb16);
  k_proj<<<dim3(64, 8), dim3(256), 0, stream>>>(attb16, w_proj, b_proj, out);
}